// Round 3
// baseline (454.189 us; speedup 1.0000x reference)
//
#include <hip/hip_runtime.h>
#include <stdint.h>

#define NSEG 50
#define HID 128
#define KDIM 2144      // 64 + 2016 + 64
#define KD2 2176       // padded to 34*64 for BK=64
#define KD2B 4352      // row bytes fp16
#define NROW 20000     // 400 * 50
#define NROW_PAD 20096 // 314 * 64
#define GATES 512

typedef __attribute__((ext_vector_type(8))) _Float16 f16x8;
typedef __attribute__((ext_vector_type(4))) float f32x4;

#define GLB_SPACE __attribute__((address_space(1)))
#define LDS_SPACE __attribute__((address_space(3)))

__device__ __forceinline__ void g2lds16(const void* g, void* l) {
    __builtin_amdgcn_global_load_lds((const GLB_SPACE uint32_t*)g,
                                     (LDS_SPACE uint32_t*)l, 16, 0, 0);
}

// ---------------- prep: cast W_ih (K-padded) and W_hh to fp16, sum biases ---------------
__global__ __launch_bounds__(256) void prep_kernel(const float* __restrict__ Wih,
                                                   const float* __restrict__ Whh,
                                                   const float* __restrict__ bih,
                                                   const float* __restrict__ bhh,
                                                   _Float16* __restrict__ wh,
                                                   _Float16* __restrict__ whh16,
                                                   float* __restrict__ bias) {
    int idx = blockIdx.x * 256 + threadIdx.x;
    const int nwih = 512 * KD2;
    const int nwhh = 512 * HID;
    if (idx < nwih) {
        int row = idx / KD2;
        int k = idx - row * KD2;
        wh[idx] = (k < KDIM) ? (_Float16)Wih[row * KDIM + k] : (_Float16)0.0f;
    } else if (idx < nwih + nwhh) {
        int q = idx - nwih;
        whh16[q] = (_Float16)Whh[q];
    } else if (idx < nwih + nwhh + 512) {
        int g = idx - nwih - nwhh;
        bias[g] = bih[g] + bhh[g];
    }
}

// ---------------- features: one block per (b, s); rank-2 levy area ----------------------
// dev_0 == 0, so S2 = (p1-p0)x(p2-p1) + (p2-p0)x(p3-p2)
__global__ __launch_bounds__(256) void feat_kernel(const float* __restrict__ x,
                                                   _Float16* __restrict__ feat) {
    int bid = blockIdx.x;          // 0..799
    int b = bid / NSEG;
    int s = bid - b * NSEG;
    int tid = threadIdx.x;

    __shared__ float pbuf[64 * 100];        // p[c][t*25+v], t in 0..3, v in 0..24
    __shared__ float2 uu[25 * 64];          // (u1,u2) per (v,c)
    __shared__ float2 vvb[25 * 64];         // (v1,v2) per (v,c)

    // load: x[b][c][4s+t][v] -> 100 contiguous floats per c
    for (int i = tid; i < 6400; i += 256) {
        int c = i / 100;
        int r = i - c * 100;
        pbuf[c * 100 + r] = x[(((size_t)b * 64 + c) * 200 + 4 * s) * 25 + r];
    }
    // zero the K-pad columns for this block's 25 rows
    if (tid < 800) {
        int v = tid >> 5;
        int k = 2144 + (tid & 31);
        size_t m = ((size_t)(b * 25 + v)) * NSEG + s;
        feat[m * KD2 + k] = (_Float16)0.0f;
    }
    __syncthreads();

    // derived vectors + lvl1/start features
    for (int i = tid; i < 1600; i += 256) {
        int v = i >> 6;
        int c = i & 63;
        float p0 = pbuf[c * 100 + v];
        float p1 = pbuf[c * 100 + 25 + v];
        float p2 = pbuf[c * 100 + 50 + v];
        float p3 = pbuf[c * 100 + 75 + v];
        uu[v * 64 + c] = make_float2(p1 - p0, p2 - p0);
        vvb[v * 64 + c] = make_float2(p2 - p1, p3 - p2);
        size_t m = ((size_t)(b * 25 + v)) * NSEG + s;
        feat[m * KD2 + c] = (_Float16)(p3 - p0);             // lvl1
        feat[m * KD2 + 2080 + c] = (_Float16)p0;             // start
    }
    __syncthreads();

    // levy: 2016 upper-triangle pairs, threads over k (coalesced 2B stores), v inner
    for (int ch = 0; ch < 8; ch++) {
        int pidx = ch * 256 + tid;
        if (pidx < 2016) {
            float disc = 16129.0f - 8.0f * (float)pidx;      // (127-2i)^2 at row starts
            int i = (int)((127.0f - sqrtf(disc)) * 0.5f);
            int off = 63 * i - (i * (i - 1)) / 2;
            while (off > pidx) { i--; off = 63 * i - (i * (i - 1)) / 2; }
            while (63 * (i + 1) - ((i + 1) * i) / 2 <= pidx) { i++; off = 63 * i - (i * (i - 1)) / 2; }
            int j = pidx - off + i + 1;
            int k = 64 + pidx;
            for (int v = 0; v < 25; v++) {
                float2 ui = uu[v * 64 + i], uj = uu[v * 64 + j];
                float2 vi = vvb[v * 64 + i], vj = vvb[v * 64 + j];
                float val = 0.5f * (ui.x * vj.x - uj.x * vi.x + ui.y * vj.y - uj.y * vi.y);
                size_t m = ((size_t)(b * 25 + v)) * NSEG + s;
                feat[m * KD2 + k] = (_Float16)val;
            }
        }
    }
}

// ---------------- GEMM: xproj = feat @ W_ih^T + bias (fp16 out) -------------------------
// BM=64, BN=256, BK=64; grid 628 (mt = bid>>1, sibling pairs share the A-tile -> LLC
// dedupes A; B (2.2 MB) is L2-resident). 4 waves, wave tile 64x64 (32 MFMA / wave / kt).
// LDS rows XOR-swizzled via the per-lane GLOBAL address of global_load_lds, so staging
// stays wave-contiguous while ds_read_b128 conflicts drop to 2-way per 16-lane phase.
__global__ __launch_bounds__(256, 2) void gemm_kernel(const _Float16* __restrict__ feat,
                                                      const _Float16* __restrict__ wh,
                                                      const float* __restrict__ bias,
                                                      _Float16* __restrict__ xproj) {
    int bid = blockIdx.x;
    int nb = bid & 1;
    int mt = bid >> 1;             // 0..313
    int m0 = mt * 64;
    int n0 = nb * 256;
    int tid = threadIdx.x;
    int wave = tid >> 6;
    int lane = tid & 63;
    int quad = lane >> 4;
    int l15 = lane & 15;
    int wn = wave * 64;

    int r8 = lane >> 3;                      // row within 8-row staging group
    int gcol = ((lane & 7) * 16) ^ (r8 * 16);  // swizzled source byte-col

    __shared__ __align__(16) _Float16 smem[(64 + 256) * 64];   // 40 KB
    char* As = (char*)smem;                  // 64 rows x 128 B
    char* Bs = (char*)smem + 64 * 128;       // 256 rows x 128 B

    const f32x4 z4 = {0.f, 0.f, 0.f, 0.f};
    f32x4 acc[4][4];
    for (int i = 0; i < 4; i++)
        for (int j = 0; j < 4; j++) acc[i][j] = z4;

    const char* featB = (const char*)feat;
    const char* whB = (const char*)wh;

    for (int kt = 0; kt < 34; kt++) {
        size_t kb = (size_t)kt * 128;
        __syncthreads();
        {
            int rb = wave * 8;
            g2lds16(featB + (size_t)(m0 + rb + r8) * KD2B + kb + gcol, As + rb * 128);
            rb += 32;
            g2lds16(featB + (size_t)(m0 + rb + r8) * KD2B + kb + gcol, As + rb * 128);
        }
        for (int it = 0; it < 8; it++) {
            int rb = it * 32 + wave * 8;
            g2lds16(whB + (size_t)(n0 + rb + r8) * KD2B + kb + gcol, Bs + rb * 128);
        }
        __syncthreads();

        for (int ks = 0; ks < 2; ks++) {
            int off = ((ks * 64) | (quad * 16)) ^ ((l15 & 7) * 16);
            f16x8 af[4], bf[4];
            for (int t = 0; t < 4; t++) {
                af[t] = *(const f16x8*)(As + (t * 16 + l15) * 128 + off);
                bf[t] = *(const f16x8*)(Bs + (wn + t * 16 + l15) * 128 + off);
            }
            for (int mtl = 0; mtl < 4; mtl++)
                for (int ntl = 0; ntl < 4; ntl++)
                    acc[mtl][ntl] = __builtin_amdgcn_mfma_f32_16x16x32_f16(af[mtl], bf[ntl], acc[mtl][ntl], 0, 0, 0);
        }
    }

    for (int ntl = 0; ntl < 4; ntl++) {
        int n = n0 + wn + ntl * 16 + l15;
        float bv = bias[n];
        for (int mtl = 0; mtl < 4; mtl++) {
            for (int r = 0; r < 4; r++) {
                int m = m0 + mtl * 16 + quad * 4 + r;   // pad rows >=20000 written, never read
                xproj[(size_t)m * GATES + n] = (_Float16)(acc[mtl][ntl][r] + bv);
            }
        }
    }
}

// ---------------- LSTM: 100 blocks x 4 seqs; wave w owns hid chunk w*16 ------------------
__global__ __launch_bounds__(512, 2) void lstm_kernel(const _Float16* __restrict__ xproj,
                                                      const _Float16* __restrict__ whh,
                                                      float* __restrict__ out) {
    int bid = blockIdx.x;        // 0..99
    int n0 = bid * 4;
    int tid = threadIdx.x;
    int wave = tid >> 6;
    int lane = tid & 63;
    int quad = lane >> 4;
    int col = lane & 15;
    int H0 = wave * 16;

    __shared__ __align__(16) _Float16 hbuf[16 * 136];   // [seq][hid]; rows 4..15 stay zero
    __shared__ float h32[128 * 4];                      // [hid][seq]

    // W_hh fragments held in VGPRs for all 50 steps. B[k][n] = whh[n][k].
    f16x8 bfrag[4][4];
    for (int gi = 0; gi < 4; gi++) {
        int n = gi * 128 + H0 + col;
        for (int q = 0; q < 4; q++)
            bfrag[gi][q] = *(const f16x8*)(whh + (size_t)n * HID + q * 32 + quad * 8);
    }
    for (int i = tid; i < 16 * 136; i += 512) hbuf[i] = (_Float16)0.0f;
    float c[4] = {0.f, 0.f, 0.f, 0.f};
    __syncthreads();

    // software-pipelined x_proj (fp16): xp holds step s, xpn prefetches s+1
    float xp[4][4];
    for (int gi = 0; gi < 4; gi++) {
        int g = gi * 128 + H0 + col;
        for (int r = 0; r < 4; r++) {
            int seq = quad * 4 + r;
            xp[gi][r] = (quad == 0)
                ? (float)xproj[((size_t)(n0 + seq) * NSEG + 0) * GATES + g] : 0.0f;
        }
    }

    const f32x4 z4 = {0.f, 0.f, 0.f, 0.f};
    for (int s = 0; s < NSEG; s++) {
        // A-frags: A[m=col][k] from h_{s-1} (rows >=4 are zero)
        f16x8 afrag[4];
        for (int q = 0; q < 4; q++)
            afrag[q] = *(const f16x8*)(&hbuf[col * 136 + q * 32 + quad * 8]);

        f32x4 acc[4];
        for (int gi = 0; gi < 4; gi++) {
            acc[gi] = z4;
            for (int q = 0; q < 4; q++)
                acc[gi] = __builtin_amdgcn_mfma_f32_16x16x32_f16(afrag[q], bfrag[gi][q], acc[gi], 0, 0, 0);
        }

        // prefetch next step's x_proj while MFMA + barriers are in flight
        float xpn[4][4];
        if (s + 1 < NSEG) {
            for (int gi = 0; gi < 4; gi++) {
                int g = gi * 128 + H0 + col;
                for (int r = 0; r < 4; r++) {
                    int seq = quad * 4 + r;
                    xpn[gi][r] = (quad == 0)
                        ? (float)xproj[((size_t)(n0 + seq) * NSEG + (s + 1)) * GATES + g] : 0.0f;
                }
            }
        }
        __syncthreads();   // all reads of hbuf done

        float hv[4];
        for (int r = 0; r < 4; r++) {
            float ip = acc[0][r] + xp[0][r];
            float fp = acc[1][r] + xp[1][r];
            float gp = acc[2][r] + xp[2][r];
            float op = acc[3][r] + xp[3][r];
            float si = __fdividef(1.0f, 1.0f + __expf(-ip));
            float sf = __fdividef(1.0f, 1.0f + __expf(-fp));
            float so = __fdividef(1.0f, 1.0f + __expf(-op));
            float eg = __expf(-2.0f * gp);
            float tg = __fdividef(1.0f - eg, 1.0f + eg);
            c[r] = sf * c[r] + si * tg;
            float ec = __expf(-2.0f * c[r]);
            float tc = __fdividef(1.0f - ec, 1.0f + ec);
            hv[r] = so * tc;
        }
        if (quad == 0) {
            for (int r = 0; r < 4; r++) {
                hbuf[r * 136 + H0 + col] = (_Float16)hv[r];
                h32[(H0 + col) * 4 + r] = hv[r];
            }
        }
        __syncthreads();   // writes visible

        // out[b][hid][s][v]: 512 values, 1 per thread
        {
            int hid = tid >> 2;
            int seq = tid & 3;
            int n = n0 + seq;
            int bb = n / 25;
            int v = n - bb * 25;
            out[(((size_t)bb * 128 + hid) * NSEG + s) * 25 + v] = h32[hid * 4 + seq];
        }

        for (int gi = 0; gi < 4; gi++)
            for (int r = 0; r < 4; r++)
                xp[gi][r] = xpn[gi][r];
    }
}

extern "C" void kernel_launch(void* const* d_in, const int* in_sizes, int n_in,
                              void* d_out, int out_size, void* d_ws, size_t ws_size,
                              hipStream_t stream) {
    const float* x = (const float*)d_in[0];
    const float* Wih = (const float*)d_in[1];
    const float* Whh = (const float*)d_in[2];
    const float* bih = (const float*)d_in[3];
    const float* bhh = (const float*)d_in[4];
    float* out = (float*)d_out;

    char* ws = (char*)d_ws;
    size_t off = 0;
    _Float16* feat = (_Float16*)(ws + off);  off += (size_t)NROW_PAD * KD2 * 2;   // 87.5 MB
    _Float16* xproj = (_Float16*)(ws + off); off += (size_t)NROW_PAD * GATES * 2; // 20.6 MB
    _Float16* wh = (_Float16*)(ws + off);    off += (size_t)512 * KD2 * 2;        // 2.2 MB
    _Float16* whh16 = (_Float16*)(ws + off); off += (size_t)512 * HID * 2;
    float* bias = (float*)(ws + off);        off += 512 * 4;

    int prep_total = 512 * KD2 + 512 * HID + 512;
    hipLaunchKernelGGL(prep_kernel, dim3((prep_total + 255) / 256), dim3(256), 0, stream,
                       Wih, Whh, bih, bhh, wh, whh16, bias);
    hipLaunchKernelGGL(feat_kernel, dim3(16 * NSEG), dim3(256), 0, stream, x, feat);
    hipLaunchKernelGGL(gemm_kernel, dim3(314 * 2), dim3(256), 0, stream, feat, wh, bias, xproj);
    hipLaunchKernelGGL(lstm_kernel, dim3(100), dim3(512), 0, stream, xproj, whh16, out);
}

// Round 4
// 277.223 us; speedup vs baseline: 1.6383x; 1.6383x over previous
//
#include <hip/hip_runtime.h>
#include <stdint.h>

#define NSEG 50
#define HID 128
#define KDIM 2144      // 64 + 2016 + 64
#define KD2 2176       // padded to 34*64 for BK=64
#define KD2B 4352      // row bytes fp16
#define NROW 20000     // 400 * 50
#define NROW_PAD 20096 // 157 * 128
#define GATES 512
#define NSEQ 400

typedef __attribute__((ext_vector_type(8))) _Float16 f16x8;
typedef __attribute__((ext_vector_type(4))) float f32x4;

#define GLB_SPACE __attribute__((address_space(1)))
#define LDS_SPACE __attribute__((address_space(3)))

__device__ __forceinline__ void g2lds16(const void* g, void* l) {
    __builtin_amdgcn_global_load_lds((const GLB_SPACE uint32_t*)g,
                                     (LDS_SPACE uint32_t*)l, 16, 0, 0);
}

// ---------------- prep: cast W_ih (K-padded) and W_hh to fp16, sum biases ---------------
__global__ __launch_bounds__(256) void prep_kernel(const float* __restrict__ Wih,
                                                   const float* __restrict__ Whh,
                                                   const float* __restrict__ bih,
                                                   const float* __restrict__ bhh,
                                                   _Float16* __restrict__ wh,
                                                   _Float16* __restrict__ whh16,
                                                   float* __restrict__ bias) {
    int idx = blockIdx.x * 256 + threadIdx.x;
    const int nwih = 512 * KD2;
    const int nwhh = 512 * HID;
    if (idx < nwih) {
        int row = idx / KD2;
        int k = idx - row * KD2;
        wh[idx] = (k < KDIM) ? (_Float16)Wih[row * KDIM + k] : (_Float16)0.0f;
    } else if (idx < nwih + nwhh) {
        int q = idx - nwih;
        whh16[q] = (_Float16)Whh[q];
    } else if (idx < nwih + nwhh + 512) {
        int g = idx - nwih - nwhh;
        bias[g] = bih[g] + bhh[g];
    }
}

// ---------------- features: one block per (b, s); rank-2 levy area ----------------------
// dev_0 == 0, so S2 = (p1-p0)x(p2-p1) + (p2-p0)x(p3-p2)
__global__ __launch_bounds__(256) void feat_kernel(const float* __restrict__ x,
                                                   _Float16* __restrict__ feat) {
    int bid = blockIdx.x;          // 0..799
    int b = bid / NSEG;
    int s = bid - b * NSEG;
    int tid = threadIdx.x;

    __shared__ float pbuf[64 * 100];        // p[c][t*25+v], t in 0..3, v in 0..24
    __shared__ float2 uu[25 * 64];          // (u1,u2) per (v,c)
    __shared__ float2 vvb[25 * 64];         // (v1,v2) per (v,c)

    // load: x[b][c][4s+t][v] -> 100 contiguous floats per c
    for (int i = tid; i < 6400; i += 256) {
        int c = i / 100;
        int r = i - c * 100;
        pbuf[c * 100 + r] = x[(((size_t)b * 64 + c) * 200 + 4 * s) * 25 + r];
    }
    // zero the K-pad columns for this block's 25 rows
    if (tid < 800) {
        int v = tid >> 5;
        int k = 2144 + (tid & 31);
        size_t m = ((size_t)(b * 25 + v)) * NSEG + s;
        feat[m * KD2 + k] = (_Float16)0.0f;
    }
    __syncthreads();

    // derived vectors + lvl1/start features
    for (int i = tid; i < 1600; i += 256) {
        int v = i >> 6;
        int c = i & 63;
        float p0 = pbuf[c * 100 + v];
        float p1 = pbuf[c * 100 + 25 + v];
        float p2 = pbuf[c * 100 + 50 + v];
        float p3 = pbuf[c * 100 + 75 + v];
        uu[v * 64 + c] = make_float2(p1 - p0, p2 - p0);
        vvb[v * 64 + c] = make_float2(p2 - p1, p3 - p2);
        size_t m = ((size_t)(b * 25 + v)) * NSEG + s;
        feat[m * KD2 + c] = (_Float16)(p3 - p0);             // lvl1
        feat[m * KD2 + 2080 + c] = (_Float16)p0;             // start
    }
    __syncthreads();

    // levy: 2016 upper-triangle pairs, threads over k (coalesced 2B stores), v inner
    for (int ch = 0; ch < 8; ch++) {
        int pidx = ch * 256 + tid;
        if (pidx < 2016) {
            float disc = 16129.0f - 8.0f * (float)pidx;      // (127-2i)^2 at row starts
            int i = (int)((127.0f - sqrtf(disc)) * 0.5f);
            int off = 63 * i - (i * (i - 1)) / 2;
            while (off > pidx) { i--; off = 63 * i - (i * (i - 1)) / 2; }
            while (63 * (i + 1) - ((i + 1) * i) / 2 <= pidx) { i++; off = 63 * i - (i * (i - 1)) / 2; }
            int j = pidx - off + i + 1;
            int k = 64 + pidx;
            for (int v = 0; v < 25; v++) {
                float2 ui = uu[v * 64 + i], uj = uu[v * 64 + j];
                float2 vi = vvb[v * 64 + i], vj = vvb[v * 64 + j];
                float val = 0.5f * (ui.x * vj.x - uj.x * vi.x + ui.y * vj.y - uj.y * vi.y);
                size_t m = ((size_t)(b * 25 + v)) * NSEG + s;
                feat[m * KD2 + k] = (_Float16)val;
            }
        }
    }
}

// ---------------- GEMM: xproj2[s][q][gate] = feat @ W_ih^T + bias (fp16 out) ------------
// BM=128, BN=128, BK=64; grid 640. bid&7-major mapping keeps the 4 n-siblings of each
// m-tile adjacent in dispatch (and on one XCD if bid%8->XCD): A-tile L2/LLC-deduped,
// fetched ~once from HBM. Epilogue remaps m=(q*50+s) -> row (s*400+q) for the LSTM.
__global__ __launch_bounds__(256, 2) void gemm_kernel(const _Float16* __restrict__ feat,
                                                      const _Float16* __restrict__ wh,
                                                      const float* __restrict__ bias,
                                                      _Float16* __restrict__ xproj2) {
    int bid = blockIdx.x;
    int x = bid & 7;
    int t = bid >> 3;
    int nb = t & 3;
    int mt = (t >> 2) * 8 + x;
    if (mt >= 157) return;
    int m0 = mt * 128;
    int n0 = nb * 128;
    int tid = threadIdx.x;
    int wave = tid >> 6;
    int lane = tid & 63;
    int quad = lane >> 4;
    int l15 = lane & 15;
    int wm = (wave & 1) * 64;
    int wn = (wave >> 1) * 64;

    int r8 = lane >> 3;                        // row within 8-row staging group
    int gcol = ((lane & 7) * 16) ^ (r8 * 16);  // XOR-swizzled source byte-col

    __shared__ __align__(16) _Float16 smem[(128 + 128) * 64];   // 32 KB
    char* As = (char*)smem;                    // 128 rows x 128 B
    char* Bs = (char*)smem + 128 * 128;        // 128 rows x 128 B

    const f32x4 z4 = {0.f, 0.f, 0.f, 0.f};
    f32x4 acc[4][4];
    for (int i = 0; i < 4; i++)
        for (int j = 0; j < 4; j++) acc[i][j] = z4;

    const char* featB = (const char*)feat;
    const char* whB = (const char*)wh;

    for (int kt = 0; kt < 34; kt++) {
        size_t kb = (size_t)kt * 128;
        __syncthreads();
        for (int it = 0; it < 4; it++) {
            int rb = it * 32 + wave * 8;
            g2lds16(featB + (size_t)(m0 + rb + r8) * KD2B + kb + gcol, As + rb * 128);
            g2lds16(whB + (size_t)(n0 + rb + r8) * KD2B + kb + gcol, Bs + rb * 128);
        }
        __syncthreads();

        for (int ks = 0; ks < 2; ks++) {
            int off = ((ks * 64) | (quad * 16)) ^ ((l15 & 7) * 16);
            f16x8 af[4], bf[4];
            for (int tt = 0; tt < 4; tt++) {
                af[tt] = *(const f16x8*)(As + (wm + tt * 16 + l15) * 128 + off);
                bf[tt] = *(const f16x8*)(Bs + (wn + tt * 16 + l15) * 128 + off);
            }
            for (int mtl = 0; mtl < 4; mtl++)
                for (int ntl = 0; ntl < 4; ntl++)
                    acc[mtl][ntl] = __builtin_amdgcn_mfma_f32_16x16x32_f16(af[mtl], bf[ntl], acc[mtl][ntl], 0, 0, 0);
        }
    }

    for (int ntl = 0; ntl < 4; ntl++) {
        int n = n0 + wn + ntl * 16 + l15;
        float bv = bias[n];
        for (int mtl = 0; mtl < 4; mtl++) {
            for (int r = 0; r < 4; r++) {
                int m = m0 + wm + mtl * 16 + quad * 4 + r;
                if (m < NROW) {
                    unsigned q = (unsigned)m / 50u;
                    unsigned s = (unsigned)m - q * 50u;
                    xproj2[((size_t)s * NSEQ + q) * GATES + n] = (_Float16)(acc[mtl][ntl][r] + bv);
                }
            }
        }
    }
}

// ---------------- LSTM: 25 blocks x 16 seqs; single barrier/step; LDS-fed ---------------
// xproj chunk for (block,s) is contiguous 16 KB -> global_load_lds double buffer, one
// step ahead. h double-buffered in LDS. h_s also dumped to hseq[s][q][hid] (compact fp16,
// quad-contiguous 32B stores fully covering 4KB chunks -> L2 merges, no amplification).
__global__ __launch_bounds__(512, 2) void lstm_kernel(const _Float16* __restrict__ xproj2,
                                                      const _Float16* __restrict__ whh,
                                                      _Float16* __restrict__ hseq) {
    int bid = blockIdx.x;        // 0..24
    int tid = threadIdx.x;
    int wave = tid >> 6;
    int lane = tid & 63;
    int quad = lane >> 4;
    int col = lane & 15;
    int H0 = wave * 16;

    __shared__ __align__(16) char xbuf[2 * 16 * 1032];   // rows padded 1024->1032 B
    __shared__ _Float16 hbuf[2][16 * 136];               // [seq][hid], padded 128->136

    // W_hh fragments held in VGPRs for all 50 steps. B[k][n] = whh[n][k].
    f16x8 bfrag[4][4];
    for (int gi = 0; gi < 4; gi++) {
        int n = gi * 128 + H0 + col;
        for (int q = 0; q < 4; q++)
            bfrag[gi][q] = *(const f16x8*)(whh + (size_t)n * HID + q * 32 + quad * 8);
    }
    for (int i = tid; i < 16 * 136; i += 512) hbuf[0][i] = (_Float16)0.0f;
    float c[4] = {0.f, 0.f, 0.f, 0.f};

    const char* xsrc = (const char*)xproj2;
    // prefetch step 0 into xbuf[0]: 16 rows of 1KB, one glds per row, 2 rows/wave
    {
        size_t base = ((size_t)0 * NSEQ + bid * 16) * 1024;
        for (int i = 0; i < 2; i++) {
            int row = wave * 2 + i;
            g2lds16(xsrc + base + (size_t)row * 1024 + lane * 16,
                    xbuf + row * 1032);
        }
    }
    __syncthreads();

    const f32x4 z4 = {0.f, 0.f, 0.f, 0.f};
    for (int s = 0; s < NSEG; s++) {
        int cur = s & 1;
        int nxt = cur ^ 1;

        // A-frags: A[m=col][k] from h_{s-1}
        f16x8 afrag[4];
        for (int q = 0; q < 4; q++)
            afrag[q] = *(const f16x8*)(&hbuf[cur][col * 136 + q * 32 + quad * 8]);

        // x_proj gates from LDS (row pad 1032B kills quad-vs-quad bank aliasing)
        float xp[4][4];
        for (int gi = 0; gi < 4; gi++)
            for (int r = 0; r < 4; r++)
                xp[gi][r] = (float)(*(const _Float16*)(xbuf + cur * 16512 +
                               (quad * 4 + r) * 1032 + (gi * 128 + H0 + col) * 2));

        f32x4 acc[4];
        for (int gi = 0; gi < 4; gi++) {
            acc[gi] = z4;
            for (int q = 0; q < 4; q++)
                acc[gi] = __builtin_amdgcn_mfma_f32_16x16x32_f16(afrag[q], bfrag[gi][q], acc[gi], 0, 0, 0);
        }

        // prefetch step s+1 into the other xbuf (drains at this step's barrier)
        if (s + 1 < NSEG) {
            size_t base = ((size_t)(s + 1) * NSEQ + bid * 16) * 1024;
            for (int i = 0; i < 2; i++) {
                int row = wave * 2 + i;
                g2lds16(xsrc + base + (size_t)row * 1024 + lane * 16,
                        xbuf + nxt * 16512 + row * 1032);
            }
        }

        float hv[4];
        for (int r = 0; r < 4; r++) {
            float ip = acc[0][r] + xp[0][r];
            float fp = acc[1][r] + xp[1][r];
            float gp = acc[2][r] + xp[2][r];
            float op = acc[3][r] + xp[3][r];
            float si = __fdividef(1.0f, 1.0f + __expf(-ip));
            float sf = __fdividef(1.0f, 1.0f + __expf(-fp));
            float so = __fdividef(1.0f, 1.0f + __expf(-op));
            float eg = __expf(-2.0f * gp);
            float tg = __fdividef(1.0f - eg, 1.0f + eg);
            c[r] = sf * c[r] + si * tg;
            float ec = __expf(-2.0f * c[r]);
            float tc = __fdividef(1.0f - ec, 1.0f + ec);
            hv[r] = so * tc;
        }
        for (int r = 0; r < 4; r++) {
            int seq = quad * 4 + r;
            hbuf[nxt][seq * 136 + H0 + col] = (_Float16)hv[r];
            hseq[((size_t)s * NSEQ + bid * 16 + seq) * HID + H0 + col] = (_Float16)hv[r];
        }
        __syncthreads();
    }
}

// ---------------- transpose: out[b][hid][s][v] = hseq[s][b*25+v][hid] -------------------
__global__ __launch_bounds__(256) void tr_kernel(const _Float16* __restrict__ hseq,
                                                 float* __restrict__ out) {
    int bid = blockIdx.x;        // 0..799 = b*50+s
    int b = bid / NSEG;
    int s = bid - b * NSEG;
    int tid = threadIdx.x;

    __shared__ _Float16 buf[25 * 130];   // [v][hid], padded 128->130

    const uint32_t* src32 = (const uint32_t*)(hseq + ((size_t)s * NSEQ + b * 25) * HID);
    uint32_t* buf32 = (uint32_t*)buf;
    for (int i = tid; i < 1600; i += 256) {       // 25 rows x 64 dwords, contiguous read
        int v = i >> 6;
        int d = i & 63;
        buf32[v * 65 + d] = src32[i];
    }
    __syncthreads();
    for (int i = tid; i < 3200; i += 256) {
        int hid = i / 25;
        int v = i - hid * 25;
        out[(((size_t)b * 128 + hid) * NSEG + s) * 25 + v] = (float)buf[v * 130 + hid];
    }
}

extern "C" void kernel_launch(void* const* d_in, const int* in_sizes, int n_in,
                              void* d_out, int out_size, void* d_ws, size_t ws_size,
                              hipStream_t stream) {
    const float* x = (const float*)d_in[0];
    const float* Wih = (const float*)d_in[1];
    const float* Whh = (const float*)d_in[2];
    const float* bih = (const float*)d_in[3];
    const float* bhh = (const float*)d_in[4];
    float* out = (float*)d_out;

    char* ws = (char*)d_ws;
    size_t off = 0;
    _Float16* feat = (_Float16*)(ws + off);   off += (size_t)NROW_PAD * KD2 * 2;    // 87.5 MB
    _Float16* xproj2 = (_Float16*)(ws + off); off += (size_t)NSEG * NSEQ * GATES * 2; // 20.5 MB
    _Float16* hseq = (_Float16*)(ws + off);   off += (size_t)NSEG * NSEQ * HID * 2;   // 5.1 MB
    _Float16* wh = (_Float16*)(ws + off);     off += (size_t)512 * KD2 * 2;           // 2.2 MB
    _Float16* whh16 = (_Float16*)(ws + off);  off += (size_t)512 * HID * 2;
    float* bias = (float*)(ws + off);         off += 512 * 4;

    int prep_total = 512 * KD2 + 512 * HID + 512;
    hipLaunchKernelGGL(prep_kernel, dim3((prep_total + 255) / 256), dim3(256), 0, stream,
                       Wih, Whh, bih, bhh, wh, whh16, bias);
    hipLaunchKernelGGL(feat_kernel, dim3(16 * NSEG), dim3(256), 0, stream, x, feat);
    hipLaunchKernelGGL(gemm_kernel, dim3(640), dim3(256), 0, stream, feat, wh, bias, xproj2);
    hipLaunchKernelGGL(lstm_kernel, dim3(25), dim3(512), 0, stream, xproj2, whh16, hseq);
    hipLaunchKernelGGL(tr_kernel, dim3(16 * NSEG), dim3(256), 0, stream, hseq, out);
}

// Round 5
// 258.060 us; speedup vs baseline: 1.7600x; 1.0743x over previous
//
#include <hip/hip_runtime.h>
#include <stdint.h>

#define NSEG 50
#define HID 128
#define KDIM 2144      // 64 + 2016 + 64
#define KD2 2176       // padded to 34*64 for BK=64
#define KD2B 4352      // row bytes fp16
#define NROW 20000     // 400 * 50
#define NROW_PAD 20096 // 157 * 128
#define GATES 512
#define NSEQ 400

typedef __attribute__((ext_vector_type(8))) _Float16 f16x8;
typedef __attribute__((ext_vector_type(4))) float f32x4;
typedef __attribute__((ext_vector_type(4))) uint32_t u32x4;

#define GLB_SPACE __attribute__((address_space(1)))
#define LDS_SPACE __attribute__((address_space(3)))

__device__ __forceinline__ void g2lds16(const void* g, void* l) {
    __builtin_amdgcn_global_load_lds((const GLB_SPACE uint32_t*)g,
                                     (LDS_SPACE uint32_t*)l, 16, 0, 0);
}

// ---------------- prep: cast W_ih (K-padded) and W_hh to fp16, sum biases ---------------
__global__ __launch_bounds__(256) void prep_kernel(const float* __restrict__ Wih,
                                                   const float* __restrict__ Whh,
                                                   const float* __restrict__ bih,
                                                   const float* __restrict__ bhh,
                                                   _Float16* __restrict__ wh,
                                                   _Float16* __restrict__ whh16,
                                                   float* __restrict__ bias) {
    int idx = blockIdx.x * 256 + threadIdx.x;
    const int nwih = 512 * KD2;
    const int nwhh = 512 * HID;
    if (idx < nwih) {
        int row = idx / KD2;
        int k = idx - row * KD2;
        wh[idx] = (k < KDIM) ? (_Float16)Wih[row * KDIM + k] : (_Float16)0.0f;
    } else if (idx < nwih + nwhh) {
        int q = idx - nwih;
        whh16[q] = (_Float16)Whh[q];
    } else if (idx < nwih + nwhh + 512) {
        int g = idx - nwih - nwhh;
        bias[g] = bih[g] + bhh[g];
    }
}

// ---------------- features: one block per (b, s); rank-2 levy area ----------------------
// dev_0 == 0, so S2 = (p1-p0)x(p2-p1) + (p2-p0)x(p3-p2)
__global__ __launch_bounds__(256) void feat_kernel(const float* __restrict__ x,
                                                   _Float16* __restrict__ feat) {
    int bid = blockIdx.x;          // 0..799
    int b = bid / NSEG;
    int s = bid - b * NSEG;
    int tid = threadIdx.x;

    __shared__ float pbuf[64 * 100];        // p[c][t*25+v], t in 0..3, v in 0..24
    __shared__ float2 uu[25 * 64];          // (u1,u2) per (v,c)
    __shared__ float2 vvb[25 * 64];         // (v1,v2) per (v,c)

    // load: x[b][c][4s+t][v] -> 100 contiguous floats per c
    for (int i = tid; i < 6400; i += 256) {
        int c = i / 100;
        int r = i - c * 100;
        pbuf[c * 100 + r] = x[(((size_t)b * 64 + c) * 200 + 4 * s) * 25 + r];
    }
    // zero the K-pad columns for this block's 25 rows
    if (tid < 800) {
        int v = tid >> 5;
        int k = 2144 + (tid & 31);
        size_t m = ((size_t)(b * 25 + v)) * NSEG + s;
        feat[m * KD2 + k] = (_Float16)0.0f;
    }
    __syncthreads();

    // derived vectors + lvl1/start features
    for (int i = tid; i < 1600; i += 256) {
        int v = i >> 6;
        int c = i & 63;
        float p0 = pbuf[c * 100 + v];
        float p1 = pbuf[c * 100 + 25 + v];
        float p2 = pbuf[c * 100 + 50 + v];
        float p3 = pbuf[c * 100 + 75 + v];
        uu[v * 64 + c] = make_float2(p1 - p0, p2 - p0);
        vvb[v * 64 + c] = make_float2(p2 - p1, p3 - p2);
        size_t m = ((size_t)(b * 25 + v)) * NSEG + s;
        feat[m * KD2 + c] = (_Float16)(p3 - p0);             // lvl1
        feat[m * KD2 + 2080 + c] = (_Float16)p0;             // start
    }
    __syncthreads();

    // levy: 2016 upper-triangle pairs, threads over k (coalesced 2B stores), v inner
    for (int ch = 0; ch < 8; ch++) {
        int pidx = ch * 256 + tid;
        if (pidx < 2016) {
            float disc = 16129.0f - 8.0f * (float)pidx;      // (127-2i)^2 at row starts
            int i = (int)((127.0f - sqrtf(disc)) * 0.5f);
            int off = 63 * i - (i * (i - 1)) / 2;
            while (off > pidx) { i--; off = 63 * i - (i * (i - 1)) / 2; }
            while (63 * (i + 1) - ((i + 1) * i) / 2 <= pidx) { i++; off = 63 * i - (i * (i - 1)) / 2; }
            int j = pidx - off + i + 1;
            int k = 64 + pidx;
            for (int v = 0; v < 25; v++) {
                float2 ui = uu[v * 64 + i], uj = uu[v * 64 + j];
                float2 vi = vvb[v * 64 + i], vj = vvb[v * 64 + j];
                float val = 0.5f * (ui.x * vj.x - uj.x * vi.x + ui.y * vj.y - uj.y * vi.y);
                size_t m = ((size_t)(b * 25 + v)) * NSEG + s;
                feat[m * KD2 + k] = (_Float16)val;
            }
        }
    }
}

// ---------------- GEMM: xproj2[s][q][gate] = feat @ W_ih^T + bias (fp16 out) ------------
// BM=128, BN=128, BK=64; grid 640. bid&7-major mapping keeps the 4 n-siblings of each
// m-tile within a 32-bid window (and on one XCD if bid%8->XCD): A-tile L2/LLC-deduped.
// Epilogue gathers the fp16 tile in LDS, then stores full 256B rows via dwordx4.
__global__ __launch_bounds__(256, 3) void gemm_kernel(const _Float16* __restrict__ feat,
                                                      const _Float16* __restrict__ wh,
                                                      const float* __restrict__ bias,
                                                      _Float16* __restrict__ xproj2) {
    int bid = blockIdx.x;
    int x = bid & 7;
    int t = bid >> 3;
    int nb = t & 3;
    int mt = (t >> 2) * 8 + x;
    if (mt >= 157) return;
    int m0 = mt * 128;
    int n0 = nb * 128;
    int tid = threadIdx.x;
    int wave = tid >> 6;
    int lane = tid & 63;
    int quad = lane >> 4;
    int l15 = lane & 15;
    int wm = (wave & 1) * 64;
    int wn = (wave >> 1) * 64;

    int r8 = lane >> 3;                        // row within 8-row staging group
    int gcol = ((lane & 7) * 16) ^ (r8 * 16);  // XOR-swizzled source byte-col

    __shared__ __align__(16) _Float16 smem[16896];   // 33 KB (K-loop 32 KB; epilogue 128x132)
    char* As = (char*)smem;                    // 128 rows x 128 B
    char* Bs = (char*)smem + 128 * 128;        // 128 rows x 128 B

    const f32x4 z4 = {0.f, 0.f, 0.f, 0.f};
    f32x4 acc[4][4];
    for (int i = 0; i < 4; i++)
        for (int j = 0; j < 4; j++) acc[i][j] = z4;

    const char* featB = (const char*)feat;
    const char* whB = (const char*)wh;

    for (int kt = 0; kt < 34; kt++) {
        size_t kb = (size_t)kt * 128;
        __syncthreads();
        for (int it = 0; it < 4; it++) {
            int rb = it * 32 + wave * 8;
            g2lds16(featB + (size_t)(m0 + rb + r8) * KD2B + kb + gcol, As + rb * 128);
            g2lds16(whB + (size_t)(n0 + rb + r8) * KD2B + kb + gcol, Bs + rb * 128);
        }
        __syncthreads();

        for (int ks = 0; ks < 2; ks++) {
            int off = ((ks * 64) | (quad * 16)) ^ ((l15 & 7) * 16);
            f16x8 af[4], bf[4];
            for (int tt = 0; tt < 4; tt++) {
                af[tt] = *(const f16x8*)(As + (wm + tt * 16 + l15) * 128 + off);
                bf[tt] = *(const f16x8*)(Bs + (wn + tt * 16 + l15) * 128 + off);
            }
            for (int mtl = 0; mtl < 4; mtl++)
                for (int ntl = 0; ntl < 4; ntl++)
                    acc[mtl][ntl] = __builtin_amdgcn_mfma_f32_16x16x32_f16(af[mtl], bf[ntl], acc[mtl][ntl], 0, 0, 0);
        }
    }

    // epilogue: stage fp16 tile in LDS (row stride 132 halfwords -> conflict-free writes)
    __syncthreads();
    for (int ntl = 0; ntl < 4; ntl++) {
        int nl = wn + ntl * 16 + l15;
        float bv = bias[n0 + nl];
        for (int mtl = 0; mtl < 4; mtl++)
            for (int r = 0; r < 4; r++) {
                int ml = wm + mtl * 16 + quad * 4 + r;
                smem[ml * 132 + nl] = (_Float16)(acc[mtl][ntl][r] + bv);
            }
    }
    __syncthreads();
    {
        int row = tid >> 1;
        int seg = tid & 1;
        int m = m0 + row;
        if (m < NROW) {
            unsigned q = (unsigned)m / 50u;
            unsigned s = (unsigned)m - q * 50u;
            const char* src = (const char*)smem + row * 264 + seg * 128;
            char* dst = (char*)xproj2 + ((size_t)s * NSEQ + q) * 1024 + (size_t)n0 * 2 + seg * 128;
            for (int i = 0; i < 8; i++)
                *(u32x4*)(dst + i * 16) = *(const u32x4*)(src + i * 16);
        }
    }
}

// ---------------- LSTM: 50 blocks x 8 seqs x 4 waves (1 wave/SIMD) ----------------------
// Replicated-A: A rows 0..15 = h[row&7] -> every quad holds a meaningful slice:
// quad q handles hid-half (q>>1), seq-half (q&1). 4 activation cells per lane, all lanes
// busy, only 4 vector-selects. hseq stores deferred one step (drain before the barrier).
__global__ __launch_bounds__(256, 1) void lstm_kernel(const _Float16* __restrict__ xproj2,
                                                      const _Float16* __restrict__ whh,
                                                      _Float16* __restrict__ hseq) {
    int bid = blockIdx.x;        // 0..49
    int tid = threadIdx.x;
    int wave = tid >> 6;         // 0..3, owns hid [wave*32, wave*32+32)
    int lane = tid & 63;
    int quad = lane >> 4;
    int col = lane & 15;
    int hh = quad >> 1;          // hid half within wave's 32
    int sq4 = (quad & 1) * 4;    // seq base for this lane's 4 regs
    int hid = wave * 32 + hh * 16 + col;   // this lane's hid (global 0..127)

    __shared__ __align__(16) char xbuf[2 * 8 * 1040];     // rows padded 1024->1040 B
    __shared__ __align__(16) _Float16 hbuf[2][8 * 136];   // [seq][hid], padded 128->136

    // B-frags: bfrag[ntl][kq], ntl = g*2 + h2; B[k][col] = whh[g*128 + wave*32 + h2*16 + col][k]
    f16x8 bfrag[8][4];
    for (int ntl = 0; ntl < 8; ntl++) {
        int g = ntl >> 1, h2 = ntl & 1;
        int n = g * 128 + wave * 32 + h2 * 16 + col;
        for (int kq = 0; kq < 4; kq++)
            bfrag[ntl][kq] = *(const f16x8*)(whh + (size_t)n * HID + kq * 32 + quad * 8);
    }
    for (int i = tid; i < 2 * 8 * 136; i += 256) ((_Float16*)hbuf)[i] = (_Float16)0.0f;
    float cst[4] = {0.f, 0.f, 0.f, 0.f};
    _Float16 hprev[4];

    const char* xsrc = (const char*)xproj2;
    // prefetch step 0 into xbuf[0]: 8 rows of 1KB; wave stages rows wave and wave+4
    {
        size_t base = (size_t)(bid * 8) * 1024;
        g2lds16(xsrc + base + (size_t)wave * 1024 + lane * 16, xbuf + wave * 1040);
        g2lds16(xsrc + base + (size_t)(wave + 4) * 1024 + lane * 16, xbuf + (wave + 4) * 1040);
    }
    __syncthreads();

    const f32x4 z4 = {0.f, 0.f, 0.f, 0.f};
    for (int s = 0; s < NSEG; s++) {
        int cur = s & 1;
        int nxt = cur ^ 1;

        // deferred global store of h_{s-1} (full step to drain before this step's barrier)
        if (s > 0) {
            for (int r = 0; r < 4; r++)
                hseq[((size_t)(s - 1) * NSEQ + bid * 8 + sq4 + r) * HID + hid] = hprev[r];
        }
        // prefetch step s+1
        if (s + 1 < NSEG) {
            size_t base = ((size_t)(s + 1) * NSEQ + bid * 8) * 1024;
            g2lds16(xsrc + base + (size_t)wave * 1024 + lane * 16,
                    xbuf + nxt * 8320 + wave * 1040);
            g2lds16(xsrc + base + (size_t)(wave + 4) * 1024 + lane * 16,
                    xbuf + nxt * 8320 + (wave + 4) * 1040);
        }

        // A-frags: A[m][k] = h[m&7][k] (replicated rows)
        f16x8 afrag[4];
        for (int kq = 0; kq < 4; kq++)
            afrag[kq] = *(const f16x8*)(&hbuf[cur][(col & 7) * 136 + kq * 32 + quad * 8]);

        // x_proj gates from LDS
        float xp[4][4];
        for (int g = 0; g < 4; g++) {
            int gc = g * 128 + hid;
            for (int r = 0; r < 4; r++)
                xp[g][r] = (float)(*(const _Float16*)(xbuf + cur * 8320 +
                               (sq4 + r) * 1040 + gc * 2));
        }

        f32x4 acc[8];
        for (int ntl = 0; ntl < 8; ntl++) {
            acc[ntl] = z4;
            for (int kq = 0; kq < 4; kq++)
                acc[ntl] = __builtin_amdgcn_mfma_f32_16x16x32_f16(afrag[kq], bfrag[ntl][kq], acc[ntl], 0, 0, 0);
        }

        // per-lane gate vectors: acc[g*2 + hh]
        f32x4 ai = hh ? acc[1] : acc[0];
        f32x4 af_ = hh ? acc[3] : acc[2];
        f32x4 ag = hh ? acc[5] : acc[4];
        f32x4 ao = hh ? acc[7] : acc[6];

        for (int r = 0; r < 4; r++) {
            float ip = ai[r] + xp[0][r];
            float fp = af_[r] + xp[1][r];
            float gp = ag[r] + xp[2][r];
            float op = ao[r] + xp[3][r];
            float si = __fdividef(1.0f, 1.0f + __expf(-ip));
            float sf = __fdividef(1.0f, 1.0f + __expf(-fp));
            float so = __fdividef(1.0f, 1.0f + __expf(-op));
            float eg = __expf(-2.0f * gp);
            float tg = __fdividef(1.0f - eg, 1.0f + eg);
            cst[r] = sf * cst[r] + si * tg;
            float ec = __expf(-2.0f * cst[r]);
            float tc = __fdividef(1.0f - ec, 1.0f + ec);
            float hv = so * tc;
            hprev[r] = (_Float16)hv;
            hbuf[nxt][(sq4 + r) * 136 + hid] = hprev[r];
        }
        __syncthreads();
    }
    // final store for s = 49
    for (int r = 0; r < 4; r++)
        hseq[((size_t)(NSEG - 1) * NSEQ + bid * 8 + sq4 + r) * HID + hid] = hprev[r];
}

// ---------------- transpose: out[b][hid][s][v] = hseq[s][b*25+v][hid] -------------------
__global__ __launch_bounds__(256) void tr_kernel(const _Float16* __restrict__ hseq,
                                                 float* __restrict__ out) {
    int bid = blockIdx.x;        // 0..799 = b*50+s
    int b = bid / NSEG;
    int s = bid - b * NSEG;
    int tid = threadIdx.x;

    __shared__ _Float16 buf[25 * 130];   // [v][hid], padded 128->130

    const uint32_t* src32 = (const uint32_t*)(hseq + ((size_t)s * NSEQ + b * 25) * HID);
    uint32_t* buf32 = (uint32_t*)buf;
    for (int i = tid; i < 1600; i += 256) {       // 25 rows x 64 dwords, contiguous read
        int v = i >> 6;
        int d = i & 63;
        buf32[v * 65 + d] = src32[i];
    }
    __syncthreads();
    for (int i = tid; i < 3200; i += 256) {
        int hid = i / 25;
        int v = i - hid * 25;
        out[(((size_t)b * 128 + hid) * NSEG + s) * 25 + v] = (float)buf[v * 130 + hid];
    }
}

extern "C" void kernel_launch(void* const* d_in, const int* in_sizes, int n_in,
                              void* d_out, int out_size, void* d_ws, size_t ws_size,
                              hipStream_t stream) {
    const float* x = (const float*)d_in[0];
    const float* Wih = (const float*)d_in[1];
    const float* Whh = (const float*)d_in[2];
    const float* bih = (const float*)d_in[3];
    const float* bhh = (const float*)d_in[4];
    float* out = (float*)d_out;

    char* ws = (char*)d_ws;
    size_t off = 0;
    _Float16* feat = (_Float16*)(ws + off);   off += (size_t)NROW_PAD * KD2 * 2;      // 87.5 MB
    _Float16* xproj2 = (_Float16*)(ws + off); off += (size_t)NSEG * NSEQ * GATES * 2; // 20.5 MB
    _Float16* hseq = (_Float16*)(ws + off);   off += (size_t)NSEG * NSEQ * HID * 2;   // 5.1 MB
    _Float16* wh = (_Float16*)(ws + off);     off += (size_t)512 * KD2 * 2;           // 2.2 MB
    _Float16* whh16 = (_Float16*)(ws + off);  off += (size_t)512 * HID * 2;
    float* bias = (float*)(ws + off);         off += 512 * 4;

    int prep_total = 512 * KD2 + 512 * HID + 512;
    hipLaunchKernelGGL(prep_kernel, dim3((prep_total + 255) / 256), dim3(256), 0, stream,
                       Wih, Whh, bih, bhh, wh, whh16, bias);
    hipLaunchKernelGGL(feat_kernel, dim3(16 * NSEG), dim3(256), 0, stream, x, feat);
    hipLaunchKernelGGL(gemm_kernel, dim3(640), dim3(256), 0, stream, feat, wh, bias, xproj2);
    hipLaunchKernelGGL(lstm_kernel, dim3(50), dim3(256), 0, stream, xproj2, whh16, hseq);
    hipLaunchKernelGGL(tr_kernel, dim3(16 * NSEG), dim3(256), 0, stream, hseq, out);
}

// Round 6
// 225.526 us; speedup vs baseline: 2.0139x; 1.1443x over previous
//
#include <hip/hip_runtime.h>
#include <stdint.h>

#define NSEG 50
#define HID 128
#define KDIM 2144      // 64 + 2016 + 64
#define KD2 2176       // padded to 34*64 for BK=64
#define KD2B 4352      // row bytes fp16
#define NROW 20000     // 400 * 50
#define NROW_PAD 20096 // 157 * 128
#define GATES 512
#define NSEQ 400

typedef __attribute__((ext_vector_type(8))) _Float16 f16x8;
typedef __attribute__((ext_vector_type(4))) float f32x4;
typedef __attribute__((ext_vector_type(4))) uint32_t u32x4;

#define GLB_SPACE __attribute__((address_space(1)))
#define LDS_SPACE __attribute__((address_space(3)))

__device__ __forceinline__ void g2lds16(const void* g, void* l) {
    __builtin_amdgcn_global_load_lds((const GLB_SPACE uint32_t*)g,
                                     (LDS_SPACE uint32_t*)l, 16, 0, 0);
}

// ---------------- prep: cast W_ih (K-padded) and W_hh to fp16, sum biases ---------------
__global__ __launch_bounds__(256) void prep_kernel(const float* __restrict__ Wih,
                                                   const float* __restrict__ Whh,
                                                   const float* __restrict__ bih,
                                                   const float* __restrict__ bhh,
                                                   _Float16* __restrict__ wh,
                                                   _Float16* __restrict__ whh16,
                                                   float* __restrict__ bias) {
    int idx = blockIdx.x * 256 + threadIdx.x;
    const int nwih = 512 * KD2;
    const int nwhh = 512 * HID;
    if (idx < nwih) {
        int row = idx / KD2;
        int k = idx - row * KD2;
        wh[idx] = (k < KDIM) ? (_Float16)Wih[row * KDIM + k] : (_Float16)0.0f;
    } else if (idx < nwih + nwhh) {
        int q = idx - nwih;
        whh16[q] = (_Float16)Whh[q];
    } else if (idx < nwih + nwhh + 512) {
        int g = idx - nwih - nwhh;
        bias[g] = bih[g] + bhh[g];
    }
}

// ---------------- features: one block per (b, s); rank-2 levy area ----------------------
// dev_0 == 0, so S2 = (p1-p0)x(p2-p1) + (p2-p0)x(p3-p2)
__global__ __launch_bounds__(256) void feat_kernel(const float* __restrict__ x,
                                                   _Float16* __restrict__ feat) {
    int bid = blockIdx.x;          // 0..799
    int b = bid / NSEG;
    int s = bid - b * NSEG;
    int tid = threadIdx.x;

    __shared__ float pbuf[64 * 100];        // p[c][t*25+v], t in 0..3, v in 0..24
    __shared__ float2 uu[25 * 64];          // (u1,u2) per (v,c)
    __shared__ float2 vvb[25 * 64];         // (v1,v2) per (v,c)

    // load: x[b][c][4s+t][v] -> 100 contiguous floats per c
    for (int i = tid; i < 6400; i += 256) {
        int c = i / 100;
        int r = i - c * 100;
        pbuf[c * 100 + r] = x[(((size_t)b * 64 + c) * 200 + 4 * s) * 25 + r];
    }
    // zero the K-pad columns for this block's 25 rows
    if (tid < 800) {
        int v = tid >> 5;
        int k = 2144 + (tid & 31);
        size_t m = ((size_t)(b * 25 + v)) * NSEG + s;
        feat[m * KD2 + k] = (_Float16)0.0f;
    }
    __syncthreads();

    // derived vectors + lvl1/start features
    for (int i = tid; i < 1600; i += 256) {
        int v = i >> 6;
        int c = i & 63;
        float p0 = pbuf[c * 100 + v];
        float p1 = pbuf[c * 100 + 25 + v];
        float p2 = pbuf[c * 100 + 50 + v];
        float p3 = pbuf[c * 100 + 75 + v];
        uu[v * 64 + c] = make_float2(p1 - p0, p2 - p0);
        vvb[v * 64 + c] = make_float2(p2 - p1, p3 - p2);
        size_t m = ((size_t)(b * 25 + v)) * NSEG + s;
        feat[m * KD2 + c] = (_Float16)(p3 - p0);             // lvl1
        feat[m * KD2 + 2080 + c] = (_Float16)p0;             // start
    }
    __syncthreads();

    // levy: 2016 upper-triangle pairs, threads over k (coalesced 2B stores), v inner
    for (int ch = 0; ch < 8; ch++) {
        int pidx = ch * 256 + tid;
        if (pidx < 2016) {
            float disc = 16129.0f - 8.0f * (float)pidx;      // (127-2i)^2 at row starts
            int i = (int)((127.0f - sqrtf(disc)) * 0.5f);
            int off = 63 * i - (i * (i - 1)) / 2;
            while (off > pidx) { i--; off = 63 * i - (i * (i - 1)) / 2; }
            while (63 * (i + 1) - ((i + 1) * i) / 2 <= pidx) { i++; off = 63 * i - (i * (i - 1)) / 2; }
            int j = pidx - off + i + 1;
            int k = 64 + pidx;
            for (int v = 0; v < 25; v++) {
                float2 ui = uu[v * 64 + i], uj = uu[v * 64 + j];
                float2 vi = vvb[v * 64 + i], vj = vvb[v * 64 + j];
                float val = 0.5f * (ui.x * vj.x - uj.x * vi.x + ui.y * vj.y - uj.y * vi.y);
                size_t m = ((size_t)(b * 25 + v)) * NSEG + s;
                feat[m * KD2 + k] = (_Float16)val;
            }
        }
    }
}

// ---------------- GEMM: xproj2[s][q][gate] = feat @ W_ih^T + bias (fp16 out) ------------
// BM=128, BN=128, BK=64; grid 640. bid&7-major mapping keeps the 4 n-siblings of each
// m-tile within a 32-bid window on one XCD residue class: A-tile L2/LLC-deduped.
// Epilogue gathers the fp16 tile in LDS, then stores full 256B rows via dwordx4.
__global__ __launch_bounds__(256, 3) void gemm_kernel(const _Float16* __restrict__ feat,
                                                      const _Float16* __restrict__ wh,
                                                      const float* __restrict__ bias,
                                                      _Float16* __restrict__ xproj2) {
    int bid = blockIdx.x;
    int x = bid & 7;
    int t = bid >> 3;
    int nb = t & 3;
    int mt = (t >> 2) * 8 + x;
    if (mt >= 157) return;
    int m0 = mt * 128;
    int n0 = nb * 128;
    int tid = threadIdx.x;
    int wave = tid >> 6;
    int lane = tid & 63;
    int quad = lane >> 4;
    int l15 = lane & 15;
    int wm = (wave & 1) * 64;
    int wn = (wave >> 1) * 64;

    int r8 = lane >> 3;                        // row within 8-row staging group
    int gcol = ((lane & 7) * 16) ^ (r8 * 16);  // XOR-swizzled source byte-col

    __shared__ __align__(16) _Float16 smem[16896];   // 33 KB (K-loop 32 KB; epilogue 128x132)
    char* As = (char*)smem;                    // 128 rows x 128 B
    char* Bs = (char*)smem + 128 * 128;        // 128 rows x 128 B

    const f32x4 z4 = {0.f, 0.f, 0.f, 0.f};
    f32x4 acc[4][4];
    for (int i = 0; i < 4; i++)
        for (int j = 0; j < 4; j++) acc[i][j] = z4;

    const char* featB = (const char*)feat;
    const char* whB = (const char*)wh;

    for (int kt = 0; kt < 34; kt++) {
        size_t kb = (size_t)kt * 128;
        __syncthreads();
        for (int it = 0; it < 4; it++) {
            int rb = it * 32 + wave * 8;
            g2lds16(featB + (size_t)(m0 + rb + r8) * KD2B + kb + gcol, As + rb * 128);
            g2lds16(whB + (size_t)(n0 + rb + r8) * KD2B + kb + gcol, Bs + rb * 128);
        }
        __syncthreads();

        for (int ks = 0; ks < 2; ks++) {
            int off = ((ks * 64) | (quad * 16)) ^ ((l15 & 7) * 16);
            f16x8 af[4], bf[4];
            for (int tt = 0; tt < 4; tt++) {
                af[tt] = *(const f16x8*)(As + (wm + tt * 16 + l15) * 128 + off);
                bf[tt] = *(const f16x8*)(Bs + (wn + tt * 16 + l15) * 128 + off);
            }
            for (int mtl = 0; mtl < 4; mtl++)
                for (int ntl = 0; ntl < 4; ntl++)
                    acc[mtl][ntl] = __builtin_amdgcn_mfma_f32_16x16x32_f16(af[mtl], bf[ntl], acc[mtl][ntl], 0, 0, 0);
        }
    }

    // epilogue: stage fp16 tile in LDS (row stride 132 halfwords -> conflict-free writes)
    __syncthreads();
    for (int ntl = 0; ntl < 4; ntl++) {
        int nl = wn + ntl * 16 + l15;
        float bv = bias[n0 + nl];
        for (int mtl = 0; mtl < 4; mtl++)
            for (int r = 0; r < 4; r++) {
                int ml = wm + mtl * 16 + quad * 4 + r;
                smem[ml * 132 + nl] = (_Float16)(acc[mtl][ntl][r] + bv);
            }
    }
    __syncthreads();
    {
        int row = tid >> 1;
        int seg = tid & 1;
        int m = m0 + row;
        if (m < NROW) {
            unsigned q = (unsigned)m / 50u;
            unsigned s = (unsigned)m - q * 50u;
            const char* src = (const char*)smem + row * 264 + seg * 128;
            char* dst = (char*)xproj2 + ((size_t)s * NSEQ + q) * 1024 + (size_t)n0 * 2 + seg * 128;
            for (int i = 0; i < 8; i++)
                *(u32x4*)(dst + i * 16) = *(const u32x4*)(src + i * 16);
        }
    }
}

// ---------------- LSTM: 100 blocks x 4 seqs x 8 waves (2 waves/SIMD) --------------------
// Wave w owns hid slice [w*16, w*16+16) for ALL 4 gates (4 gate-tiles, 16 MFMA/step).
// A rows replicated h[row&3] -> every quad holds all 4 seq-rows; quad q takes seq q
// (1 activation cell/lane, extracted with 8 cndmasks). 2 waves/SIMD overlap latency.
__global__ __launch_bounds__(512, 2) void lstm_kernel(const _Float16* __restrict__ xproj2,
                                                      const _Float16* __restrict__ whh,
                                                      _Float16* __restrict__ hseq) {
    int bid = blockIdx.x;        // 0..99
    int tid = threadIdx.x;
    int wave = tid >> 6;         // 0..7
    int lane = tid & 63;
    int quad = lane >> 4;        // = this lane's seq
    int col = lane & 15;
    int hid = wave * 16 + col;   // this lane's hid

    __shared__ __align__(16) char xbuf[2 * 4 * 1040];     // rows padded 1024->1040 B
    __shared__ __align__(16) _Float16 hbuf[2][4 * 136];   // [seq][hid], padded 128->136

    // B-frags: bfrag[g][kq]; B[k][n] = whh[g*128 + hid][k]
    f16x8 bfrag[4][4];
    for (int g = 0; g < 4; g++) {
        int n = g * 128 + hid;
        for (int kq = 0; kq < 4; kq++)
            bfrag[g][kq] = *(const f16x8*)(whh + (size_t)n * HID + kq * 32 + quad * 8);
    }
    for (int i = tid; i < 2 * 4 * 136; i += 512) ((_Float16*)hbuf)[i] = (_Float16)0.0f;
    float cst = 0.0f;
    _Float16 hprev = (_Float16)0.0f;

    const char* xsrc = (const char*)xproj2;
    // prefetch step 0 into xbuf[0]: 4 rows of 1KB; waves 0..3 stage one row each
    if (wave < 4)
        g2lds16(xsrc + (size_t)(bid * 4 + wave) * 1024 + lane * 16, xbuf + wave * 1040);
    __syncthreads();

    const f32x4 z4 = {0.f, 0.f, 0.f, 0.f};
    for (int s = 0; s < NSEG; s++) {
        int cur = s & 1;
        int nxt = cur ^ 1;

        // deferred global store of h_{s-1} (full step to drain before this step's barrier)
        if (s > 0)
            hseq[((size_t)(s - 1) * NSEQ + bid * 4 + quad) * HID + hid] = hprev;
        // prefetch step s+1
        if (s + 1 < NSEG && wave < 4)
            g2lds16(xsrc + ((size_t)(s + 1) * NSEQ + bid * 4 + wave) * 1024 + lane * 16,
                    xbuf + nxt * 4160 + wave * 1040);

        // A-frags: A[m][k] = h[m&3][k] (replicated rows)
        f16x8 afrag[4];
        for (int kq = 0; kq < 4; kq++)
            afrag[kq] = *(const f16x8*)(&hbuf[cur][(col & 3) * 136 + kq * 32 + quad * 8]);

        // x_proj gates from LDS: 4 scalar reads for this lane's (seq=quad, hid)
        float xp[4];
        for (int g = 0; g < 4; g++)
            xp[g] = (float)(*(const _Float16*)(xbuf + cur * 4160 +
                           quad * 1040 + (g * 128 + hid) * 2));

        f32x4 acc[4];
        for (int g = 0; g < 4; g++) {
            acc[g] = z4;
            for (int kq = 0; kq < 4; kq++)
                acc[g] = __builtin_amdgcn_mfma_f32_16x16x32_f16(afrag[kq], bfrag[g][kq], acc[g], 0, 0, 0);
        }

        // extract element [quad] of each gate vector (C row quad*4+r = seq r)
        float gv[4];
        for (int g = 0; g < 4; g++) {
            float lo = (quad & 1) ? acc[g][1] : acc[g][0];
            float hi = (quad & 1) ? acc[g][3] : acc[g][2];
            gv[g] = (quad & 2) ? hi : lo;
        }

        float ip = gv[0] + xp[0];
        float fp = gv[1] + xp[1];
        float gp = gv[2] + xp[2];
        float op = gv[3] + xp[3];
        float si = __fdividef(1.0f, 1.0f + __expf(-ip));
        float sf = __fdividef(1.0f, 1.0f + __expf(-fp));
        float so = __fdividef(1.0f, 1.0f + __expf(-op));
        float eg = __expf(-2.0f * gp);
        float tg = __fdividef(1.0f - eg, 1.0f + eg);
        cst = sf * cst + si * tg;
        float ec = __expf(-2.0f * cst);
        float tc = __fdividef(1.0f - ec, 1.0f + ec);
        float hv = so * tc;
        hprev = (_Float16)hv;
        hbuf[nxt][quad * 136 + hid] = hprev;
        __syncthreads();
    }
    // final store for s = 49
    hseq[((size_t)(NSEG - 1) * NSEQ + bid * 4 + quad) * HID + hid] = hprev;
}

// ---------------- transpose: out[b][hid][s][v] = hseq[s][b*25+v][hid] -------------------
__global__ __launch_bounds__(256) void tr_kernel(const _Float16* __restrict__ hseq,
                                                 float* __restrict__ out) {
    int bid = blockIdx.x;        // 0..799 = b*50+s
    int b = bid / NSEG;
    int s = bid - b * NSEG;
    int tid = threadIdx.x;

    __shared__ _Float16 buf[25 * 130];   // [v][hid], padded 128->130

    const uint32_t* src32 = (const uint32_t*)(hseq + ((size_t)s * NSEQ + b * 25) * HID);
    uint32_t* buf32 = (uint32_t*)buf;
    for (int i = tid; i < 1600; i += 256) {       // 25 rows x 64 dwords, contiguous read
        int v = i >> 6;
        int d = i & 63;
        buf32[v * 65 + d] = src32[i];
    }
    __syncthreads();
    for (int i = tid; i < 3200; i += 256) {
        int hid = i / 25;
        int v = i - hid * 25;
        out[(((size_t)b * 128 + hid) * NSEG + s) * 25 + v] = (float)buf[v * 130 + hid];
    }
}

extern "C" void kernel_launch(void* const* d_in, const int* in_sizes, int n_in,
                              void* d_out, int out_size, void* d_ws, size_t ws_size,
                              hipStream_t stream) {
    const float* x = (const float*)d_in[0];
    const float* Wih = (const float*)d_in[1];
    const float* Whh = (const float*)d_in[2];
    const float* bih = (const float*)d_in[3];
    const float* bhh = (const float*)d_in[4];
    float* out = (float*)d_out;

    char* ws = (char*)d_ws;
    size_t off = 0;
    _Float16* feat = (_Float16*)(ws + off);   off += (size_t)NROW_PAD * KD2 * 2;      // 87.5 MB
    _Float16* xproj2 = (_Float16*)(ws + off); off += (size_t)NSEG * NSEQ * GATES * 2; // 20.5 MB
    _Float16* hseq = (_Float16*)(ws + off);   off += (size_t)NSEG * NSEQ * HID * 2;   // 5.1 MB
    _Float16* wh = (_Float16*)(ws + off);     off += (size_t)512 * KD2 * 2;           // 2.2 MB
    _Float16* whh16 = (_Float16*)(ws + off);  off += (size_t)512 * HID * 2;
    float* bias = (float*)(ws + off);         off += 512 * 4;

    int prep_total = 512 * KD2 + 512 * HID + 512;
    hipLaunchKernelGGL(prep_kernel, dim3((prep_total + 255) / 256), dim3(256), 0, stream,
                       Wih, Whh, bih, bhh, wh, whh16, bias);
    hipLaunchKernelGGL(feat_kernel, dim3(16 * NSEG), dim3(256), 0, stream, x, feat);
    hipLaunchKernelGGL(gemm_kernel, dim3(640), dim3(256), 0, stream, feat, wh, bias, xproj2);
    hipLaunchKernelGGL(lstm_kernel, dim3(100), dim3(512), 0, stream, xproj2, whh16, hseq);
    hipLaunchKernelGGL(tr_kernel, dim3(16 * NSEG), dim3(256), 0, stream, hseq, out);
}